// Round 1
// baseline (339.091 us; speedup 1.0000x reference)
//
#include <hip/hip_runtime.h>
#include <math.h>

// Problem constants
#define DMODEL 96
#define DIN    192
#define NST    16
#define RK     6
#define KDIR   4
#define HH     64
#define WWI    64
#define LLEN   4096   // H*W
#define BB     2
#define BP_TOT 8192   // B*L
#define SCH    64     // scan chunks
#define TCH    64     // steps per chunk (L/SCH)

// ---------------------------------------------------------------------------
// K1: in_proj  xz[bp,e] = sum_c x[bp,c] * Wp[e,c];  e<192 -> xi, e>=192 -> z
// block 192 threads, 8 positions/block, thread computes cols t and t+192.
__global__ __launch_bounds__(192) void k_inproj(const float* __restrict__ x,
                                                const float* __restrict__ Wp,
                                                float* __restrict__ xi,
                                                float* __restrict__ z)
{
    __shared__ float xT[96 * 12];  // [c][pp], stride 12
    const int t  = threadIdx.x;
    const int p0 = blockIdx.x * 8;
    #pragma unroll
    for (int it = 0; it < 4; ++it) {
        int idx = t + it * 192;
        int c = idx % 96, pp = idx / 96;
        xT[c * 12 + pp] = x[(p0 + pp) * 96 + c];
    }
    __syncthreads();

    float acc0[8], acc1[8];
    #pragma unroll
    for (int i = 0; i < 8; ++i) { acc0[i] = 0.f; acc1[i] = 0.f; }
    const float* w0p = Wp + t * 96;
    const float* w1p = Wp + (t + 192) * 96;
    for (int k = 0; k < 96; ++k) {
        float w0 = w0p[k], w1 = w1p[k];
        float4 a = *(const float4*)&xT[k * 12];
        float4 b = *(const float4*)&xT[k * 12 + 4];
        float xv[8] = {a.x, a.y, a.z, a.w, b.x, b.y, b.z, b.w};
        #pragma unroll
        for (int i = 0; i < 8; ++i) {
            acc0[i] += w0 * xv[i];
            acc1[i] += w1 * xv[i];
        }
    }
    #pragma unroll
    for (int i = 0; i < 8; ++i) {
        xi[(p0 + i) * 192 + t] = acc0[i];
        z [(p0 + i) * 192 + t] = acc1[i];
    }
}

// ---------------------------------------------------------------------------
// K2: depthwise 3x3 conv (SAME) + bias + SiLU.  (b,p,d) layout, coalesced in d.
__global__ __launch_bounds__(256) void k_conv(const float* __restrict__ xi,
                                              const float* __restrict__ cw,
                                              const float* __restrict__ cb,
                                              float* __restrict__ xc)
{
    int tid = blockIdx.x * 256 + threadIdx.x;  // BP_TOT*192 total
    int d  = tid % 192;
    int bp = tid / 192;
    int p  = bp & 4095;
    int b  = bp >> 12;
    int h  = p >> 6, w = p & 63;
    float s = cb[d];
    #pragma unroll
    for (int ky = 0; ky < 3; ++ky) {
        int hh = h + ky - 1;
        if (hh < 0 || hh >= 64) continue;
        #pragma unroll
        for (int kx = 0; kx < 3; ++kx) {
            int ww = w + kx - 1;
            if (ww < 0 || ww >= 64) continue;
            s += xi[((size_t)b * 4096 + hh * 64 + ww) * 192 + d] * cw[d * 9 + ky * 3 + kx];
        }
    }
    xc[tid] = s * (1.f / (1.f + __expf(-s)));  // SiLU
}

// ---------------------------------------------------------------------------
// K3: x_proj for all 4 directions at once (weights concatenated along rows).
// xdbl[bp, col] = sum_d xc[bp,d] * xpw_flat[col*192+d],  col in [0,152)
// block 256: 6 groups x 38 col-quads; 48 positions/block; K=192 fully staged.
__global__ __launch_bounds__(256) void k_xdbl(const float* __restrict__ xc,
                                              const float* __restrict__ xpw,
                                              float* __restrict__ xdbl)
{
    __shared__ float xl[192 * 52];  // [c][pp], stride 52
    const int t  = threadIdx.x;
    const int p0 = blockIdx.x * 48;
    #pragma unroll
    for (int it = 0; it < 36; ++it) {
        int idx = t + it * 256;
        int c = idx % 192, pp = idx / 192;
        int bp = p0 + pp;
        xl[c * 52 + pp] = (bp < BP_TOT) ? xc[(size_t)bp * 192 + c] : 0.f;
    }
    __syncthreads();

    int g = t / 38, cq = t % 38;
    if (g >= 6) return;
    float acc[4][8];
    #pragma unroll
    for (int j = 0; j < 4; ++j)
        #pragma unroll
        for (int i = 0; i < 8; ++i) acc[j][i] = 0.f;

    const float* wr0 = xpw + (4 * cq + 0) * 192;
    const float* wr1 = xpw + (4 * cq + 1) * 192;
    const float* wr2 = xpw + (4 * cq + 2) * 192;
    const float* wr3 = xpw + (4 * cq + 3) * 192;
    for (int k = 0; k < 192; ++k) {
        float4 a = *(const float4*)&xl[k * 52 + g * 8];
        float4 b = *(const float4*)&xl[k * 52 + g * 8 + 4];
        float xv[8] = {a.x, a.y, a.z, a.w, b.x, b.y, b.z, b.w};
        float w0 = wr0[k], w1 = wr1[k], w2 = wr2[k], w3 = wr3[k];
        #pragma unroll
        for (int i = 0; i < 8; ++i) {
            acc[0][i] += w0 * xv[i];
            acc[1][i] += w1 * xv[i];
            acc[2][i] += w2 * xv[i];
            acc[3][i] += w3 * xv[i];
        }
    }
    #pragma unroll
    for (int i = 0; i < 8; ++i) {
        int bp = p0 + g * 8 + i;
        if (bp < BP_TOT) {
            float4 v = make_float4(acc[0][i], acc[1][i], acc[2][i], acc[3][i]);
            *(float4*)&xdbl[(size_t)bp * 152 + 4 * cq] = v;
        }
    }
}

// ---------------------------------------------------------------------------
// scan-order -> position permutation (H=W=64)
__device__ __forceinline__ int perm_pos(int k, int l)
{
    if (k == 0) return l;
    if (k == 1) return ((l & 63) << 6) | (l >> 6);
    if (k == 2) return 4095 - l;
    int lr = 4095 - l;
    return ((lr & 63) << 6) | (lr >> 6);
}

__device__ __forceinline__ float softplusf(float x)
{
    return (x > 20.f) ? x : log1pf(__expf(x));
}

// ---------------------------------------------------------------------------
// K4: scan pass 1 — per-chunk local recurrence from h=0; store prod(a) and h_end.
// grid: (b*4+k)*64+s blocks, 192 threads (one per d). h[16] in registers.
__global__ __launch_bounds__(192) void k_scan1(const float* __restrict__ xc,
                                               const float* __restrict__ xdbl,
                                               const float* __restrict__ dtw,
                                               const float* __restrict__ dtb,
                                               const float* __restrict__ Alog,
                                               float* __restrict__ hend,
                                               float* __restrict__ prodA)
{
    const int t   = threadIdx.x;
    const int blk = blockIdx.x;
    const int s = blk & 63, k = (blk >> 6) & 3, b = blk >> 8;
    const int kd = k * 192 + t;

    float A[16], wdt[6];
    #pragma unroll
    for (int n = 0; n < 16; ++n) A[n] = -__expf(Alog[kd * 16 + n]);
    #pragma unroll
    for (int r = 0; r < 6; ++r) wdt[r] = dtw[kd * 6 + r];
    const float bias = dtb[kd];

    float h[16], ap[16];
    #pragma unroll
    for (int n = 0; n < 16; ++n) { h[n] = 0.f; ap[n] = 1.f; }

    const float* xdb = xdbl + (size_t)b * 4096 * 152 + k * 38;
    const float* xcb = xc   + (size_t)b * 4096 * 192;
    const int l0 = s * TCH;
    for (int l = l0; l < l0 + TCH; ++l) {
        int p = perm_pos(k, l);
        const float* row = xdb + (size_t)p * 152;
        float xv = bias;
        #pragma unroll
        for (int r = 0; r < 6; ++r) xv += row[r] * wdt[r];
        float delta = softplusf(xv);
        float u  = xcb[(size_t)p * 192 + t];
        float du = delta * u;
        #pragma unroll
        for (int n = 0; n < 16; ++n) {
            float a = __expf(delta * A[n]);
            ap[n] *= a;
            h[n] = h[n] * a + du * row[6 + n];
        }
    }
    size_t base = (size_t)blk * 3072 + t * 16;
    #pragma unroll
    for (int i = 0; i < 4; ++i) {
        *(float4*)&hend [base + 4 * i] = make_float4(h[4*i], h[4*i+1], h[4*i+2], h[4*i+3]);
        *(float4*)&prodA[base + 4 * i] = make_float4(ap[4*i], ap[4*i+1], ap[4*i+2], ap[4*i+3]);
    }
}

// ---------------------------------------------------------------------------
// K5: scan pass 2 — serial composition over chunks per (b,k,d,n).
__global__ __launch_bounds__(256) void k_scan2(const float* __restrict__ hend,
                                               const float* __restrict__ prodA,
                                               float* __restrict__ hinit)
{
    int tid = blockIdx.x * 256 + threadIdx.x;  // 24576 lanes
    int n  = tid & 15;
    int d  = (tid >> 4) % 192;
    int bk = tid / (192 * 16);
    size_t base = (size_t)bk * SCH * 3072 + d * 16 + n;
    float carry = 0.f;
    for (int s = 0; s < SCH; ++s) {
        size_t a = base + (size_t)s * 3072;
        hinit[a] = carry;
        carry = prodA[a] * carry + hend[a];
    }
}

// ---------------------------------------------------------------------------
// K6: scan pass 3 — re-run chunks from proper h_init, emit y (+D*u skip),
// merge all directions into position-indexed y via atomics.
__global__ __launch_bounds__(192) void k_scan3(const float* __restrict__ xc,
                                               const float* __restrict__ xdbl,
                                               const float* __restrict__ dtw,
                                               const float* __restrict__ dtb,
                                               const float* __restrict__ Alog,
                                               const float* __restrict__ Ds,
                                               const float* __restrict__ hinit,
                                               float* __restrict__ y)
{
    const int t   = threadIdx.x;
    const int blk = blockIdx.x;
    const int s = blk & 63, k = (blk >> 6) & 3, b = blk >> 8;
    const int kd = k * 192 + t;

    float A[16], wdt[6];
    #pragma unroll
    for (int n = 0; n < 16; ++n) A[n] = -__expf(Alog[kd * 16 + n]);
    #pragma unroll
    for (int r = 0; r < 6; ++r) wdt[r] = dtw[kd * 6 + r];
    const float bias = dtb[kd];
    const float Dk   = Ds[kd];

    float h[16];
    size_t hbase = (size_t)blk * 3072 + t * 16;
    #pragma unroll
    for (int i = 0; i < 4; ++i) {
        float4 v = *(const float4*)&hinit[hbase + 4 * i];
        h[4*i] = v.x; h[4*i+1] = v.y; h[4*i+2] = v.z; h[4*i+3] = v.w;
    }

    const float* xdb = xdbl + (size_t)b * 4096 * 152 + k * 38;
    const float* xcb = xc   + (size_t)b * 4096 * 192;
    float* yb = y + (size_t)b * 4096 * 192;
    const int l0 = s * TCH;
    for (int l = l0; l < l0 + TCH; ++l) {
        int p = perm_pos(k, l);
        const float* row = xdb + (size_t)p * 152;
        float xv = bias;
        #pragma unroll
        for (int r = 0; r < 6; ++r) xv += row[r] * wdt[r];
        float delta = softplusf(xv);
        float u  = xcb[(size_t)p * 192 + t];
        float du = delta * u;
        float acc = Dk * u;
        #pragma unroll
        for (int n = 0; n < 16; ++n) {
            float a = __expf(delta * A[n]);
            h[n] = h[n] * a + du * row[6 + n];
            acc += h[n] * row[22 + n];
        }
        unsafeAtomicAdd(&yb[(size_t)p * 192 + t], acc);
    }
}

// ---------------------------------------------------------------------------
// K7: LayerNorm(192) + out_norm affine + SiLU(z) gate
__global__ __launch_bounds__(192) void k_lngate(const float* __restrict__ y,
                                                const float* __restrict__ z,
                                                const float* __restrict__ onw,
                                                const float* __restrict__ onb,
                                                float* __restrict__ yg)
{
    const int t  = threadIdx.x;
    const int bp = blockIdx.x;
    float yv = y[(size_t)bp * 192 + t];
    float s1 = yv, s2 = yv * yv;
    #pragma unroll
    for (int off = 32; off; off >>= 1) {
        s1 += __shfl_xor(s1, off, 64);
        s2 += __shfl_xor(s2, off, 64);
    }
    __shared__ float rs[3], rq[3];
    int wv = t >> 6;
    if ((t & 63) == 0) { rs[wv] = s1; rq[wv] = s2; }
    __syncthreads();
    float tot  = rs[0] + rs[1] + rs[2];
    float totq = rq[0] + rq[1] + rq[2];
    float mean = tot * (1.f / 192.f);
    float var  = totq * (1.f / 192.f) - mean * mean;
    float rinv = rsqrtf(var + 1e-5f);
    float yn = (yv - mean) * rinv * onw[t] + onb[t];
    float zv = z[(size_t)bp * 192 + t];
    float sig = 1.f / (1.f + __expf(-zv));
    yg[(size_t)bp * 192 + t] = yn * (zv * sig);
}

// ---------------------------------------------------------------------------
// K8: out_proj  out[bp,c] = sum_d yg[bp,d] * Wo[c,d]; N=96, K=192
// block 256: 5 groups x 48 col-pairs; 40 positions/block.
__global__ __launch_bounds__(256) void k_outproj(const float* __restrict__ yg,
                                                 const float* __restrict__ Wo,
                                                 float* __restrict__ out)
{
    __shared__ float xl[192 * 44];
    const int t  = threadIdx.x;
    const int p0 = blockIdx.x * 40;
    #pragma unroll
    for (int it = 0; it < 30; ++it) {
        int idx = t + it * 256;
        int c = idx % 192, pp = idx / 192;
        int bp = p0 + pp;
        xl[c * 44 + pp] = (bp < BP_TOT) ? yg[(size_t)bp * 192 + c] : 0.f;
    }
    __syncthreads();

    int g = t / 48, cp = t % 48;
    if (g >= 5) return;
    float acc0[8], acc1[8];
    #pragma unroll
    for (int i = 0; i < 8; ++i) { acc0[i] = 0.f; acc1[i] = 0.f; }
    const float* w0p = Wo + (2 * cp) * 192;
    const float* w1p = Wo + (2 * cp + 1) * 192;
    for (int k = 0; k < 192; ++k) {
        float4 a = *(const float4*)&xl[k * 44 + g * 8];
        float4 b = *(const float4*)&xl[k * 44 + g * 8 + 4];
        float xv[8] = {a.x, a.y, a.z, a.w, b.x, b.y, b.z, b.w};
        float w0 = w0p[k], w1 = w1p[k];
        #pragma unroll
        for (int i = 0; i < 8; ++i) {
            acc0[i] += w0 * xv[i];
            acc1[i] += w1 * xv[i];
        }
    }
    #pragma unroll
    for (int i = 0; i < 8; ++i) {
        int bp = p0 + g * 8 + i;
        if (bp < BP_TOT) {
            out[(size_t)bp * 96 + 2 * cp]     = acc0[i];
            out[(size_t)bp * 96 + 2 * cp + 1] = acc1[i];
        }
    }
}

// ---------------------------------------------------------------------------
extern "C" void kernel_launch(void* const* d_in, const int* in_sizes, int n_in,
                              void* d_out, int out_size, void* d_ws, size_t ws_size,
                              hipStream_t stream)
{
    const float* x    = (const float*)d_in[0];
    const float* Wp   = (const float*)d_in[1];
    const float* cw   = (const float*)d_in[2];
    const float* cb   = (const float*)d_in[3];
    const float* xpw  = (const float*)d_in[4];
    const float* dtw  = (const float*)d_in[5];
    const float* dtb  = (const float*)d_in[6];
    const float* Alog = (const float*)d_in[7];
    const float* Ds   = (const float*)d_in[8];
    const float* onw  = (const float*)d_in[9];
    const float* onb  = (const float*)d_in[10];
    const float* Wo   = (const float*)d_in[11];
    float* out = (float*)d_out;

    const size_t NBP = (size_t)BP_TOT * 192;  // 1,572,864 floats
    float* WS    = (float*)d_ws;
    float* xc    = WS;                  // conv output (b,p,d)
    float* zb    = WS + NBP;            // gate z
    float* xiy   = WS + 2 * NBP;        // xi (conv in), later y accumulator
    float* xdbl  = WS + 3 * NBP;        // (b,p,152): 1,245,184 floats
    float* hend  = WS + 3 * NBP + 1245184;
    float* prodA = hend + NBP;          // (b,k,s,d,n): 8*64*3072 = NBP floats
    float* hinit = prodA + NBP;
    float* yg    = hend;                // reuse hend after pass 2/3

    k_inproj <<<1024, 192, 0, stream>>>(x, Wp, xiy, zb);
    k_conv   <<<6144, 256, 0, stream>>>(xiy, cw, cb, xc);
    hipMemsetAsync(xiy, 0, NBP * sizeof(float), stream);  // y accumulator
    k_xdbl   <<<171, 256, 0, stream>>>(xc, xpw, xdbl);
    k_scan1  <<<512, 192, 0, stream>>>(xc, xdbl, dtw, dtb, Alog, hend, prodA);
    k_scan2  <<<96, 256, 0, stream>>>(hend, prodA, hinit);
    k_scan3  <<<512, 192, 0, stream>>>(xc, xdbl, dtw, dtb, Alog, Ds, hinit, xiy);
    k_lngate <<<8192, 192, 0, stream>>>(xiy, zb, onw, onb, yg);
    k_outproj<<<205, 256, 0, stream>>>(yg, Wo, out);
}

// Round 2
// 258.778 us; speedup vs baseline: 1.3104x; 1.3104x over previous
//
#include <hip/hip_runtime.h>
#include <math.h>

// Problem constants
#define DMODEL 96
#define DIN    192
#define NST    16
#define RK     6
#define KDIR   4
#define HH     64
#define WWI    64
#define LLEN   4096   // H*W
#define BB     2
#define BP_TOT 8192   // B*L
#define SCH    128    // scan chunks
#define TCH    32     // steps per chunk (L/SCH)

// ---------------------------------------------------------------------------
// K1: in_proj  xz[bp,e] = sum_c x[bp,c] * Wp[e,c];  e<192 -> xi, e>=192 -> z
__global__ __launch_bounds__(192) void k_inproj(const float* __restrict__ x,
                                                const float* __restrict__ Wp,
                                                float* __restrict__ xi,
                                                float* __restrict__ z)
{
    __shared__ float xT[96 * 12];  // [c][pp], stride 12
    const int t  = threadIdx.x;
    const int p0 = blockIdx.x * 8;
    #pragma unroll
    for (int it = 0; it < 4; ++it) {
        int idx = t + it * 192;
        int c = idx % 96, pp = idx / 96;
        xT[c * 12 + pp] = x[(p0 + pp) * 96 + c];
    }
    __syncthreads();

    float acc0[8], acc1[8];
    #pragma unroll
    for (int i = 0; i < 8; ++i) { acc0[i] = 0.f; acc1[i] = 0.f; }
    const float* w0p = Wp + t * 96;
    const float* w1p = Wp + (t + 192) * 96;
    for (int k = 0; k < 96; ++k) {
        float w0 = w0p[k], w1 = w1p[k];
        float4 a = *(const float4*)&xT[k * 12];
        float4 b = *(const float4*)&xT[k * 12 + 4];
        float xv[8] = {a.x, a.y, a.z, a.w, b.x, b.y, b.z, b.w};
        #pragma unroll
        for (int i = 0; i < 8; ++i) {
            acc0[i] += w0 * xv[i];
            acc1[i] += w1 * xv[i];
        }
    }
    #pragma unroll
    for (int i = 0; i < 8; ++i) {
        xi[(p0 + i) * 192 + t] = acc0[i];
        z [(p0 + i) * 192 + t] = acc1[i];
    }
}

// ---------------------------------------------------------------------------
// K2: depthwise 3x3 conv (SAME) + bias + SiLU.  (b,p,d) layout, coalesced in d.
__global__ __launch_bounds__(256) void k_conv(const float* __restrict__ xi,
                                              const float* __restrict__ cw,
                                              const float* __restrict__ cb,
                                              float* __restrict__ xc)
{
    int tid = blockIdx.x * 256 + threadIdx.x;  // BP_TOT*192 total
    int d  = tid % 192;
    int bp = tid / 192;
    int p  = bp & 4095;
    int b  = bp >> 12;
    int h  = p >> 6, w = p & 63;
    float s = cb[d];
    #pragma unroll
    for (int ky = 0; ky < 3; ++ky) {
        int hh = h + ky - 1;
        if (hh < 0 || hh >= 64) continue;
        #pragma unroll
        for (int kx = 0; kx < 3; ++kx) {
            int ww = w + kx - 1;
            if (ww < 0 || ww >= 64) continue;
            s += xi[((size_t)b * 4096 + hh * 64 + ww) * 192 + d] * cw[d * 9 + ky * 3 + kx];
        }
    }
    xc[tid] = s * (1.f / (1.f + __expf(-s)));  // SiLU
}

// ---------------------------------------------------------------------------
// K3: x_proj for all 4 directions at once (weights concatenated along rows).
__global__ __launch_bounds__(256) void k_xdbl(const float* __restrict__ xc,
                                              const float* __restrict__ xpw,
                                              float* __restrict__ xdbl)
{
    __shared__ float xl[192 * 52];  // [c][pp], stride 52
    const int t  = threadIdx.x;
    const int p0 = blockIdx.x * 48;
    #pragma unroll
    for (int it = 0; it < 36; ++it) {
        int idx = t + it * 256;
        int c = idx % 192, pp = idx / 192;
        int bp = p0 + pp;
        xl[c * 52 + pp] = (bp < BP_TOT) ? xc[(size_t)bp * 192 + c] : 0.f;
    }
    __syncthreads();

    int g = t / 38, cq = t % 38;
    if (g >= 6) return;
    float acc[4][8];
    #pragma unroll
    for (int j = 0; j < 4; ++j)
        #pragma unroll
        for (int i = 0; i < 8; ++i) acc[j][i] = 0.f;

    const float* wr0 = xpw + (4 * cq + 0) * 192;
    const float* wr1 = xpw + (4 * cq + 1) * 192;
    const float* wr2 = xpw + (4 * cq + 2) * 192;
    const float* wr3 = xpw + (4 * cq + 3) * 192;
    for (int k = 0; k < 192; ++k) {
        float4 a = *(const float4*)&xl[k * 52 + g * 8];
        float4 b = *(const float4*)&xl[k * 52 + g * 8 + 4];
        float xv[8] = {a.x, a.y, a.z, a.w, b.x, b.y, b.z, b.w};
        float w0 = wr0[k], w1 = wr1[k], w2 = wr2[k], w3 = wr3[k];
        #pragma unroll
        for (int i = 0; i < 8; ++i) {
            acc[0][i] += w0 * xv[i];
            acc[1][i] += w1 * xv[i];
            acc[2][i] += w2 * xv[i];
            acc[3][i] += w3 * xv[i];
        }
    }
    #pragma unroll
    for (int i = 0; i < 8; ++i) {
        int bp = p0 + g * 8 + i;
        if (bp < BP_TOT) {
            float4 v = make_float4(acc[0][i], acc[1][i], acc[2][i], acc[3][i]);
            *(float4*)&xdbl[(size_t)bp * 152 + 4 * cq] = v;
        }
    }
}

// ---------------------------------------------------------------------------
// scan-order -> position permutation (H=W=64)
__device__ __forceinline__ int perm_pos(int k, int l)
{
    if (k == 0) return l;
    if (k == 1) return ((l & 63) << 6) | (l >> 6);
    if (k == 2) return 4095 - l;
    int lr = 4095 - l;
    return ((lr & 63) << 6) | (lr >> 6);
}

__device__ __forceinline__ float softplus_fast(float x)
{
    // log(1+e^x); for x>15, == x to < 3e-7
    float r = __logf(1.f + __expf(x));
    return (x > 15.f) ? x : r;
}

// binary power chain: aa[n] = e1^(n+1), depth 4
__device__ __forceinline__ void pow_chain(float e1, float* aa)
{
    float e2 = e1 * e1, e4 = e2 * e2, e8 = e4 * e4, e16 = e8 * e8;
    float e3 = e2 * e1, e5 = e4 * e1, e6 = e4 * e2, e7 = e4 * e3;
    aa[0] = e1;  aa[1] = e2;  aa[2] = e3;  aa[3] = e4;
    aa[4] = e5;  aa[5] = e6;  aa[6] = e7;  aa[7] = e8;
    aa[8] = e8 * e1;  aa[9] = e8 * e2;  aa[10] = e8 * e3;  aa[11] = e8 * e4;
    aa[12] = e8 * e5; aa[13] = e8 * e6; aa[14] = e8 * e7;  aa[15] = e16;
}

// ---------------------------------------------------------------------------
// K4: scan pass 1 — per-chunk local recurrence from h=0; store prodA and h_end.
// grid: ((b*4+k)*SCH+s) blocks, 192 threads (one per d). h[16] in registers.
// prodA[n] = exp(A[n]*sum_delta)  (exact identity, no per-step products).
__global__ __launch_bounds__(192) void k_scan1(const float* __restrict__ xc,
                                               const float* __restrict__ xdbl,
                                               const float* __restrict__ dtw,
                                               const float* __restrict__ dtb,
                                               const float* __restrict__ Alog,
                                               float* __restrict__ hend,
                                               float* __restrict__ prodA)
{
    __shared__ float sm[TCH * 24];  // per step: B[0..15], dt[16..21]
    const int t   = threadIdx.x;
    const int blk = blockIdx.x;
    const int s = blk & (SCH - 1), k = (blk >> 7) & 3, b = blk >> 9;
    const int kd = k * 192 + t;
    const int l0 = s * TCH;

    const float* xdb = xdbl + (size_t)b * 4096 * 152 + k * 38;
    const float* xcb = xc   + (size_t)b * 4096 * 192;

    // stage chunk rows into LDS
    for (int idx = t; idx < TCH * 22; idx += 192) {
        int st = idx / 22, c = idx % 22;
        int gcol = (c < 16) ? (6 + c) : (c - 16);
        sm[st * 24 + c] = xdb[(size_t)perm_pos(k, l0 + st) * 152 + gcol];
    }

    const float A0 = -__expf(Alog[kd * 16]);
    bool fast = true;
    #pragma unroll
    for (int n = 1; n < 16; ++n) {
        float An = -__expf(Alog[kd * 16 + n]);
        fast = fast && (fabsf(An - (float)(n + 1) * A0) <= 1e-3f * fabsf(An));
    }
    float wdt[6];
    #pragma unroll
    for (int r = 0; r < 6; ++r) wdt[r] = dtw[kd * 6 + r];
    const float bias = dtb[kd];

    float h[16];
    #pragma unroll
    for (int n = 0; n < 16; ++n) h[n] = 0.f;
    float sdelta = 0.f;

    __syncthreads();

    int p_cur = perm_pos(k, l0);
    float u = xcb[(size_t)p_cur * 192 + t];

    if (fast) {
        for (int st = 0; st < TCH; ++st) {
            int p_next = (st + 1 < TCH) ? perm_pos(k, l0 + st + 1) : p_cur;
            float u_next = xcb[(size_t)p_next * 192 + t];
            const float* r = &sm[st * 24];
            float4 dq = *(const float4*)(r + 16);
            float xv = bias + dq.x * wdt[0] + dq.y * wdt[1] + dq.z * wdt[2]
                            + dq.w * wdt[3] + r[20] * wdt[4] + r[21] * wdt[5];
            float delta = softplus_fast(xv);
            sdelta += delta;
            float du = delta * u;
            float aa[16];
            pow_chain(__expf(delta * A0), aa);
            float4 b0 = *(const float4*)(r), b1 = *(const float4*)(r + 4);
            float4 b2 = *(const float4*)(r + 8), b3 = *(const float4*)(r + 12);
            float bv[16] = {b0.x, b0.y, b0.z, b0.w, b1.x, b1.y, b1.z, b1.w,
                            b2.x, b2.y, b2.z, b2.w, b3.x, b3.y, b3.z, b3.w};
            #pragma unroll
            for (int n = 0; n < 16; ++n) h[n] = fmaf(h[n], aa[n], du * bv[n]);
            u = u_next; p_cur = p_next;
        }
    } else {
        for (int st = 0; st < TCH; ++st) {
            int p_next = (st + 1 < TCH) ? perm_pos(k, l0 + st + 1) : p_cur;
            float u_next = xcb[(size_t)p_next * 192 + t];
            const float* r = &sm[st * 24];
            float xv = bias;
            #pragma unroll
            for (int j = 0; j < 6; ++j) xv += r[16 + j] * wdt[j];
            float delta = softplus_fast(xv);
            sdelta += delta;
            float du = delta * u;
            #pragma unroll
            for (int n = 0; n < 16; ++n) {
                float An = -__expf(Alog[kd * 16 + n]);
                h[n] = fmaf(h[n], __expf(delta * An), du * r[n]);
            }
            u = u_next; p_cur = p_next;
        }
    }

    size_t base = (size_t)blk * 3072 + t * 16;
    float ap[16];
    if (fast) {
        pow_chain(__expf(sdelta * A0), ap);
    } else {
        #pragma unroll
        for (int n = 0; n < 16; ++n)
            ap[n] = __expf(-__expf(Alog[kd * 16 + n]) * sdelta);
    }
    #pragma unroll
    for (int i = 0; i < 4; ++i) {
        *(float4*)&hend [base + 4 * i] = make_float4(h[4*i], h[4*i+1], h[4*i+2], h[4*i+3]);
        *(float4*)&prodA[base + 4 * i] = make_float4(ap[4*i], ap[4*i+1], ap[4*i+2], ap[4*i+3]);
    }
}

// ---------------------------------------------------------------------------
// K5: scan pass 2 — serial composition over chunks per (b,k,d,n).
// Overwrites prodA with h_init per chunk (aliasing saves one workspace array).
__global__ __launch_bounds__(256) void k_scan2(const float* __restrict__ hend,
                                               float* __restrict__ prodA)
{
    int tid = blockIdx.x * 256 + threadIdx.x;  // 24576 lanes
    int n  = tid & 15;
    int d  = (tid >> 4) % 192;
    int bk = tid / (192 * 16);
    size_t base = (size_t)bk * SCH * 3072 + d * 16 + n;
    float carry = 0.f;
    for (int s = 0; s < SCH; ++s) {
        size_t a = base + (size_t)s * 3072;
        float pa = prodA[a];
        float he = hend[a];
        prodA[a] = carry;            // becomes h_init
        carry = fmaf(pa, carry, he);
    }
}

// ---------------------------------------------------------------------------
// K6: scan pass 3 — re-run chunks from proper h_init, emit y (+D*u skip),
// merge all directions into position-indexed y via atomics.
__global__ __launch_bounds__(192) void k_scan3(const float* __restrict__ xc,
                                               const float* __restrict__ xdbl,
                                               const float* __restrict__ dtw,
                                               const float* __restrict__ dtb,
                                               const float* __restrict__ Alog,
                                               const float* __restrict__ Ds,
                                               const float* __restrict__ hinit,
                                               float* __restrict__ y)
{
    __shared__ float sm[TCH * 40];  // per step: B[0..15], C[16..31], dt[32..37]
    const int t   = threadIdx.x;
    const int blk = blockIdx.x;
    const int s = blk & (SCH - 1), k = (blk >> 7) & 3, b = blk >> 9;
    const int kd = k * 192 + t;
    const int l0 = s * TCH;

    const float* xdb = xdbl + (size_t)b * 4096 * 152 + k * 38;
    const float* xcb = xc   + (size_t)b * 4096 * 192;
    float* yb = y + (size_t)b * 4096 * 192;

    for (int idx = t; idx < TCH * 38; idx += 192) {
        int st = idx / 38, c = idx % 38;
        int gcol = (c < 32) ? (6 + c) : (c - 32);
        sm[st * 40 + c] = xdb[(size_t)perm_pos(k, l0 + st) * 152 + gcol];
    }

    const float A0 = -__expf(Alog[kd * 16]);
    bool fast = true;
    #pragma unroll
    for (int n = 1; n < 16; ++n) {
        float An = -__expf(Alog[kd * 16 + n]);
        fast = fast && (fabsf(An - (float)(n + 1) * A0) <= 1e-3f * fabsf(An));
    }
    float wdt[6];
    #pragma unroll
    for (int r = 0; r < 6; ++r) wdt[r] = dtw[kd * 6 + r];
    const float bias = dtb[kd];
    const float Dk   = Ds[kd];

    float h[16];
    size_t hbase = (size_t)blk * 3072 + t * 16;
    #pragma unroll
    for (int i = 0; i < 4; ++i) {
        float4 v = *(const float4*)&hinit[hbase + 4 * i];
        h[4*i] = v.x; h[4*i+1] = v.y; h[4*i+2] = v.z; h[4*i+3] = v.w;
    }

    __syncthreads();

    int p_cur = perm_pos(k, l0);
    float u = xcb[(size_t)p_cur * 192 + t];

    if (fast) {
        for (int st = 0; st < TCH; ++st) {
            int p_next = (st + 1 < TCH) ? perm_pos(k, l0 + st + 1) : p_cur;
            float u_next = xcb[(size_t)p_next * 192 + t];
            const float* r = &sm[st * 40];
            float4 dq = *(const float4*)(r + 32);
            float xv = bias + dq.x * wdt[0] + dq.y * wdt[1] + dq.z * wdt[2]
                            + dq.w * wdt[3] + r[36] * wdt[4] + r[37] * wdt[5];
            float delta = softplus_fast(xv);
            float du = delta * u;
            float aa[16];
            pow_chain(__expf(delta * A0), aa);
            float4 b0 = *(const float4*)(r), b1 = *(const float4*)(r + 4);
            float4 b2 = *(const float4*)(r + 8), b3 = *(const float4*)(r + 12);
            float4 c0 = *(const float4*)(r + 16), c1 = *(const float4*)(r + 20);
            float4 c2 = *(const float4*)(r + 24), c3 = *(const float4*)(r + 28);
            float bv[16] = {b0.x, b0.y, b0.z, b0.w, b1.x, b1.y, b1.z, b1.w,
                            b2.x, b2.y, b2.z, b2.w, b3.x, b3.y, b3.z, b3.w};
            float cv[16] = {c0.x, c0.y, c0.z, c0.w, c1.x, c1.y, c1.z, c1.w,
                            c2.x, c2.y, c2.z, c2.w, c3.x, c3.y, c3.z, c3.w};
            float acc = Dk * u;
            #pragma unroll
            for (int n = 0; n < 16; ++n) {
                h[n] = fmaf(h[n], aa[n], du * bv[n]);
                acc  = fmaf(h[n], cv[n], acc);
            }
            unsafeAtomicAdd(&yb[(size_t)p_cur * 192 + t], acc);
            u = u_next; p_cur = p_next;
        }
    } else {
        for (int st = 0; st < TCH; ++st) {
            int p_next = (st + 1 < TCH) ? perm_pos(k, l0 + st + 1) : p_cur;
            float u_next = xcb[(size_t)p_next * 192 + t];
            const float* r = &sm[st * 40];
            float xv = bias;
            #pragma unroll
            for (int j = 0; j < 6; ++j) xv += r[32 + j] * wdt[j];
            float delta = softplus_fast(xv);
            float du = delta * u;
            float acc = Dk * u;
            #pragma unroll
            for (int n = 0; n < 16; ++n) {
                float An = -__expf(Alog[kd * 16 + n]);
                h[n] = fmaf(h[n], __expf(delta * An), du * r[n]);
                acc  = fmaf(h[n], r[16 + n], acc);
            }
            unsafeAtomicAdd(&yb[(size_t)p_cur * 192 + t], acc);
            u = u_next; p_cur = p_next;
        }
    }
}

// ---------------------------------------------------------------------------
// K7: LayerNorm(192) + out_norm affine + SiLU(z) gate
__global__ __launch_bounds__(192) void k_lngate(const float* __restrict__ y,
                                                const float* __restrict__ z,
                                                const float* __restrict__ onw,
                                                const float* __restrict__ onb,
                                                float* __restrict__ yg)
{
    const int t  = threadIdx.x;
    const int bp = blockIdx.x;
    float yv = y[(size_t)bp * 192 + t];
    float s1 = yv, s2 = yv * yv;
    #pragma unroll
    for (int off = 32; off; off >>= 1) {
        s1 += __shfl_xor(s1, off, 64);
        s2 += __shfl_xor(s2, off, 64);
    }
    __shared__ float rs[3], rq[3];
    int wv = t >> 6;
    if ((t & 63) == 0) { rs[wv] = s1; rq[wv] = s2; }
    __syncthreads();
    float tot  = rs[0] + rs[1] + rs[2];
    float totq = rq[0] + rq[1] + rq[2];
    float mean = tot * (1.f / 192.f);
    float var  = totq * (1.f / 192.f) - mean * mean;
    float rinv = rsqrtf(var + 1e-5f);
    float yn = (yv - mean) * rinv * onw[t] + onb[t];
    float zv = z[(size_t)bp * 192 + t];
    float sig = 1.f / (1.f + __expf(-zv));
    yg[(size_t)bp * 192 + t] = yn * (zv * sig);
}

// ---------------------------------------------------------------------------
// K8: out_proj  out[bp,c] = sum_d yg[bp,d] * Wo[c,d]; N=96, K=192
__global__ __launch_bounds__(256) void k_outproj(const float* __restrict__ yg,
                                                 const float* __restrict__ Wo,
                                                 float* __restrict__ out)
{
    __shared__ float xl[192 * 44];
    const int t  = threadIdx.x;
    const int p0 = blockIdx.x * 40;
    #pragma unroll
    for (int it = 0; it < 30; ++it) {
        int idx = t + it * 256;
        int c = idx % 192, pp = idx / 192;
        int bp = p0 + pp;
        xl[c * 44 + pp] = (bp < BP_TOT) ? yg[(size_t)bp * 192 + c] : 0.f;
    }
    __syncthreads();

    int g = t / 48, cp = t % 48;
    if (g >= 5) return;
    float acc0[8], acc1[8];
    #pragma unroll
    for (int i = 0; i < 8; ++i) { acc0[i] = 0.f; acc1[i] = 0.f; }
    const float* w0p = Wo + (2 * cp) * 192;
    const float* w1p = Wo + (2 * cp + 1) * 192;
    for (int k = 0; k < 192; ++k) {
        float4 a = *(const float4*)&xl[k * 44 + g * 8];
        float4 b = *(const float4*)&xl[k * 44 + g * 8 + 4];
        float xv[8] = {a.x, a.y, a.z, a.w, b.x, b.y, b.z, b.w};
        float w0 = w0p[k], w1 = w1p[k];
        #pragma unroll
        for (int i = 0; i < 8; ++i) {
            acc0[i] += w0 * xv[i];
            acc1[i] += w1 * xv[i];
        }
    }
    #pragma unroll
    for (int i = 0; i < 8; ++i) {
        int bp = p0 + g * 8 + i;
        if (bp < BP_TOT) {
            out[(size_t)bp * 96 + 2 * cp]     = acc0[i];
            out[(size_t)bp * 96 + 2 * cp + 1] = acc1[i];
        }
    }
}

// ---------------------------------------------------------------------------
extern "C" void kernel_launch(void* const* d_in, const int* in_sizes, int n_in,
                              void* d_out, int out_size, void* d_ws, size_t ws_size,
                              hipStream_t stream)
{
    const float* x    = (const float*)d_in[0];
    const float* Wp   = (const float*)d_in[1];
    const float* cw   = (const float*)d_in[2];
    const float* cb   = (const float*)d_in[3];
    const float* xpw  = (const float*)d_in[4];
    const float* dtw  = (const float*)d_in[5];
    const float* dtb  = (const float*)d_in[6];
    const float* Alog = (const float*)d_in[7];
    const float* Ds   = (const float*)d_in[8];
    const float* onw  = (const float*)d_in[9];
    const float* onb  = (const float*)d_in[10];
    const float* Wo   = (const float*)d_in[11];
    float* out = (float*)d_out;

    const size_t NBP  = (size_t)BP_TOT * 192;       // 1,572,864 floats
    const size_t NXD  = (size_t)BP_TOT * 152;       // 1,245,184 floats
    const size_t NSC  = (size_t)BB * 4 * SCH * 3072; // 3,145,728 floats
    float* WS    = (float*)d_ws;
    float* xc    = WS;                  // conv output (b,p,d)
    float* zb    = WS + NBP;            // gate z
    float* xiy   = WS + 2 * NBP;        // xi (conv in), later y accumulator
    float* xdbl  = WS + 3 * NBP;        // (b,p,152)
    float* hend  = xdbl + NXD;
    float* prodA = hend + NSC;          // after pass2: h_init
    float* yg    = hend;                // reuse hend after pass 3

    k_inproj <<<1024, 192, 0, stream>>>(x, Wp, xiy, zb);
    k_conv   <<<6144, 256, 0, stream>>>(xiy, cw, cb, xc);
    hipMemsetAsync(xiy, 0, NBP * sizeof(float), stream);  // y accumulator
    k_xdbl   <<<171, 256, 0, stream>>>(xc, xpw, xdbl);
    k_scan1  <<<1024, 192, 0, stream>>>(xc, xdbl, dtw, dtb, Alog, hend, prodA);
    k_scan2  <<<96, 256, 0, stream>>>(hend, prodA);
    k_scan3  <<<1024, 192, 0, stream>>>(xc, xdbl, dtw, dtb, Alog, Ds, prodA, xiy);
    k_lngate <<<8192, 192, 0, stream>>>(xiy, zb, onw, onb, yg);
    k_outproj<<<205, 256, 0, stream>>>(yg, Wo, out);
}